// Round 1
// baseline (96.879 us; speedup 1.0000x reference)
//
#include <hip/hip_runtime.h>

// PINN beam fields: per point x compute MLP (1->16->16->2, tanh) value and
// derivatives up to 3rd order via forward-mode Taylor propagation, then
// u, w, w_x, N = EA*(u_x + 0.5 w_x^2), M = -EI*w_xx, Q = -EI*w_xxx + N*w_x.

#define EA_C 1.0e4f
#define EI_C 1.0e2f
// L = 1.0 in the reference -> z = x, dz/dx = 1.

__device__ __forceinline__ float fast_tanh(float a) {
    // tanh(a) = 1 - 2/(exp(2a)+1); saturates cleanly at +-1 (no inf/inf NaN).
    float e = __expf(2.0f * a);
    return 1.0f - 2.0f / (e + 1.0f);
}

__global__ __launch_bounds__(256) void pinn_fields_kernel(
    const float* __restrict__ x,
    const float* __restrict__ W1,   // (16,1)
    const float* __restrict__ b1,   // (16,)
    const float* __restrict__ W2,   // (16,16) row-major
    const float* __restrict__ b2,   // (16,)
    const float* __restrict__ W3,   // (2,16) row-major
    const float* __restrict__ b3,   // (2,)
    float* __restrict__ out,        // 6 * n, concatenated (u,w,wx,N,M,Q)
    int n)
{
    int idx = blockIdx.x * blockDim.x + threadIdx.x;
    if (idx >= n) return;

    float z = x[idx];  // z = x / L, L = 1

    // ---- layer 1: h = tanh(W1*z + b1); a' = W1 (a''=a'''=0) ----
    float h0[16], h1[16], h2[16], h3[16];
#pragma unroll
    for (int j = 0; j < 16; ++j) {
        float c  = W1[j];                 // da/dx
        float a  = fmaf(W1[j], z, b1[j]);
        float t  = fast_tanh(a);
        float s  = 1.0f - t * t;          // sech^2
        float c2 = c * c;
        h0[j] = t;
        h1[j] = s * c;                            // t' * a'
        h2[j] = -2.0f * t * s * c2;               // t'' * a'^2
        h3[j] = s * (4.0f * t * t - 2.0f * s) * c2 * c;  // t''' * a'^3
    }

    // ---- layer 2 + layer 3 fused over rows i ----
    float uacc0 = b3[0], uacc1 = 0.0f;
    float wacc0 = b3[1], wacc1 = 0.0f, wacc2 = 0.0f, wacc3 = 0.0f;
#pragma unroll
    for (int i = 0; i < 16; ++i) {
        float a0 = b2[i], a1 = 0.0f, a2 = 0.0f, a3 = 0.0f;
#pragma unroll
        for (int j = 0; j < 16; ++j) {
            float wv = W2[i * 16 + j];    // wave-uniform -> s_load / K$ hit
            a0 = fmaf(wv, h0[j], a0);
            a1 = fmaf(wv, h1[j], a1);
            a2 = fmaf(wv, h2[j], a2);
            a3 = fmaf(wv, h3[j], a3);
        }
        float t  = fast_tanh(a0);
        float s  = 1.0f - t * t;
        float d1 = s;                               // tanh'
        float d2 = -2.0f * t * s;                   // tanh''
        float d3 = s * (4.0f * t * t - 2.0f * s);   // tanh'''
        // Faa di Bruno up to 3rd order:
        float g0 = t;
        float g1 = d1 * a1;
        float g2 = fmaf(d2, a1 * a1, d1 * a2);
        float g3 = d3 * a1 * a1 * a1 + 3.0f * d2 * a1 * a2 + d1 * a3;

        float w3u = W3[i];        // W3[0][i]
        float w3w = W3[16 + i];   // W3[1][i]
        uacc0 = fmaf(w3u, g0, uacc0);
        uacc1 = fmaf(w3u, g1, uacc1);
        wacc0 = fmaf(w3w, g0, wacc0);
        wacc1 = fmaf(w3w, g1, wacc1);
        wacc2 = fmaf(w3w, g2, wacc2);
        wacc3 = fmaf(w3w, g3, wacc3);
    }

    float u    = uacc0;
    float ux   = uacc1;
    float w    = wacc0;
    float wx   = wacc1;
    float wxx  = wacc2;
    float wxxx = wacc3;

    float Nax = EA_C * fmaf(0.5f * wx, wx, ux);
    float Mb  = -EI_C * wxx;
    float Qs  = fmaf(Nax, wx, -EI_C * wxxx);

    out[idx]         = u;
    out[n + idx]     = w;
    out[2 * n + idx] = wx;
    out[3 * n + idx] = Nax;
    out[4 * n + idx] = Mb;
    out[5 * n + idx] = Qs;
}

extern "C" void kernel_launch(void* const* d_in, const int* in_sizes, int n_in,
                              void* d_out, int out_size, void* d_ws, size_t ws_size,
                              hipStream_t stream) {
    const float* x  = (const float*)d_in[0];
    const float* W1 = (const float*)d_in[1];
    const float* b1 = (const float*)d_in[2];
    const float* W2 = (const float*)d_in[3];
    const float* b2 = (const float*)d_in[4];
    const float* W3 = (const float*)d_in[5];
    const float* b3 = (const float*)d_in[6];
    float* out = (float*)d_out;
    int n = in_sizes[0];

    int block = 256;
    int grid = (n + block - 1) / block;
    pinn_fields_kernel<<<grid, block, 0, stream>>>(x, W1, b1, W2, b2, W3, b3, out, n);
}

// Round 2
// 87.920 us; speedup vs baseline: 1.1019x; 1.1019x over previous
//
#include <hip/hip_runtime.h>

// PINN beam fields: per point x compute MLP (1->16->16->2, tanh) value and
// derivatives up to 3rd order via forward-mode Taylor propagation, then
// u, w, w_x, N = EA*(u_x + 0.5 w_x^2), M = -EI*w_xx, Q = -EI*w_xxx + N*w_x.
//
// R2: (a) tanh via v_rcp_f32 instead of IEEE divide (~10 instrs -> 1);
//     (b) Taylor channels paired into float2 so the backend emits
//         v_pk_fma_f32 (packed fp32 FMA, gfx90a+/gfx950) -> halves the
//         1024-FMA layer-2 core's instruction count.

#define EA_C 1.0e4f
#define EI_C 1.0e2f
// L = 1.0 in the reference -> z = x, dz/dx = 1.

typedef float v2f __attribute__((ext_vector_type(2)));

__device__ __forceinline__ v2f mk2(float a, float b) {
    v2f r; r.x = a; r.y = b; return r;
}

__device__ __forceinline__ float fast_tanh(float a) {
    // tanh(a) = 1 - 2/(exp(2a)+1); v_exp + v_rcp, saturates cleanly at +-1.
    float e = __expf(2.0f * a);
    float r = __builtin_amdgcn_rcpf(e + 1.0f);
    return fmaf(-2.0f, r, 1.0f);
}

__global__ __launch_bounds__(256) void pinn_fields_kernel(
    const float* __restrict__ x,
    const float* __restrict__ W1,   // (16,1)
    const float* __restrict__ b1,   // (16,)
    const float* __restrict__ W2,   // (16,16) row-major
    const float* __restrict__ b2,   // (16,)
    const float* __restrict__ W3,   // (2,16) row-major
    const float* __restrict__ b3,   // (2,)
    float* __restrict__ out,        // 6 * n, concatenated (u,w,wx,N,M,Q)
    int n)
{
    int idx = blockIdx.x * blockDim.x + threadIdx.x;
    if (idx >= n) return;

    float z = x[idx];  // z = x / L, L = 1

    // ---- layer 1: h = tanh(W1*z + b1); a' = W1 (a''=a'''=0) ----
    // Taylor channels packed: h01 = {h, h_x}, h23 = {h_xx, h_xxx}
    v2f h01[16], h23[16];
#pragma unroll
    for (int j = 0; j < 16; ++j) {
        float c  = W1[j];                 // da/dx
        float a  = fmaf(c, z, b1[j]);
        float t  = fast_tanh(a);
        float s  = 1.0f - t * t;          // sech^2 = tanh'
        float c2 = c * c;
        h01[j] = mk2(t, s * c);
        h23[j] = mk2(-2.0f * t * s * c2,                      // t'' * c^2
                     s * (4.0f * t * t - 2.0f * s) * c2 * c); // t''' * c^3
    }

    // ---- layer 2 + layer 3 fused over rows i ----
    v2f uacc   = mk2(b3[0], 0.0f);   // {u, u_x}
    v2f wacc01 = mk2(b3[1], 0.0f);   // {w, w_x}
    v2f wacc23 = mk2(0.0f, 0.0f);    // {w_xx, w_xxx}
#pragma unroll
    for (int i = 0; i < 16; ++i) {
        v2f A01 = mk2(b2[i], 0.0f);
        v2f A23 = mk2(0.0f, 0.0f);
#pragma unroll
        for (int j = 0; j < 16; ++j) {
            float wv = W2[i * 16 + j];    // wave-uniform -> scalar load
            v2f wv2 = mk2(wv, wv);
            A01 = __builtin_elementwise_fma(wv2, h01[j], A01);  // v_pk_fma_f32
            A23 = __builtin_elementwise_fma(wv2, h23[j], A23);
        }
        float a1 = A01.y, a2 = A23.x, a3 = A23.y;
        float t  = fast_tanh(A01.x);
        float s  = 1.0f - t * t;                    // d1
        float d2 = -2.0f * t * s;
        float d3 = s * (4.0f * t * t - 2.0f * s);
        // Faa di Bruno up to 3rd order:
        float g0 = t;
        float g1 = s * a1;
        float g2 = fmaf(d2, a1 * a1, s * a2);
        float g3 = d3 * a1 * a1 * a1 + 3.0f * d2 * a1 * a2 + s * a3;

        v2f g01 = mk2(g0, g1);
        v2f g23 = mk2(g2, g3);
        float w3u = W3[i];        // W3[0][i]
        float w3w = W3[16 + i];   // W3[1][i]
        uacc   = __builtin_elementwise_fma(mk2(w3u, w3u), g01, uacc);
        wacc01 = __builtin_elementwise_fma(mk2(w3w, w3w), g01, wacc01);
        wacc23 = __builtin_elementwise_fma(mk2(w3w, w3w), g23, wacc23);
    }

    float u    = uacc.x;
    float ux   = uacc.y;
    float w    = wacc01.x;
    float wx   = wacc01.y;
    float wxx  = wacc23.x;
    float wxxx = wacc23.y;

    float Nax = EA_C * fmaf(0.5f * wx, wx, ux);
    float Mb  = -EI_C * wxx;
    float Qs  = fmaf(Nax, wx, -EI_C * wxxx);

    out[idx]         = u;
    out[n + idx]     = w;
    out[2 * n + idx] = wx;
    out[3 * n + idx] = Nax;
    out[4 * n + idx] = Mb;
    out[5 * n + idx] = Qs;
}

extern "C" void kernel_launch(void* const* d_in, const int* in_sizes, int n_in,
                              void* d_out, int out_size, void* d_ws, size_t ws_size,
                              hipStream_t stream) {
    const float* x  = (const float*)d_in[0];
    const float* W1 = (const float*)d_in[1];
    const float* b1 = (const float*)d_in[2];
    const float* W2 = (const float*)d_in[3];
    const float* b2 = (const float*)d_in[4];
    const float* W3 = (const float*)d_in[5];
    const float* b3 = (const float*)d_in[6];
    float* out = (float*)d_out;
    int n = in_sizes[0];

    int block = 256;
    int grid = (n + block - 1) / block;
    pinn_fields_kernel<<<grid, block, 0, stream>>>(x, W1, b1, W2, b2, W3, b3, out, n);
}

// Round 3
// 86.927 us; speedup vs baseline: 1.1145x; 1.0114x over previous
//
#include <hip/hip_runtime.h>

// PINN beam fields: per point x compute MLP (1->16->16->2, tanh) value and
// derivatives up to 3rd order via forward-mode Taylor propagation, then
// u, w, w_x, N = EA*(u_x + 0.5 w_x^2), M = -EI*w_xx, Q = -EI*w_xxx + N*w_x.
//
// R3: fully packed-fp32 dataflow.
//  - layer 1 packed over hidden-unit PAIRS (j-packing): H0..H3[jp] hold
//    {h(2jp), h(2jp+1)} etc. -> feeds layer-2 pk_fma directly, no repack.
//  - layer 2: per row, 4 v2f accumulators (one per Taylor channel), each
//    j-pair contributes 4 v_pk_fma_f32; horizontal sum at the end.
//  - Faa di Bruno + layer 3 packed over ROW pairs.
//  - tanh via __expf + v_rcp_f32; d3 = s*(4-6s) using t^2 = 1-s.

#define EA_C 1.0e4f
#define EI_C 1.0e2f
// L = 1.0 in the reference -> z = x, dz/dx = 1.

typedef float v2f __attribute__((ext_vector_type(2)));

__device__ __forceinline__ v2f pk_fma(v2f a, v2f b, v2f c) {
    return __builtin_elementwise_fma(a, b, c);
}
__device__ __forceinline__ v2f splat2(float a) { v2f r; r.x = a; r.y = a; return r; }
__device__ __forceinline__ v2f mk2(float a, float b) { v2f r; r.x = a; r.y = b; return r; }

// packed tanh: 2 scalar exp/rcp (transcendentals don't pack), packed finish
__device__ __forceinline__ v2f pk_tanh(v2f a) {
    float e0 = __expf(2.0f * a.x);          // v_mul(const) + v_exp
    float e1 = __expf(2.0f * a.y);
    float r0 = __builtin_amdgcn_rcpf(e0 + 1.0f);
    float r1 = __builtin_amdgcn_rcpf(e1 + 1.0f);
    return pk_fma(splat2(-2.0f), mk2(r0, r1), splat2(1.0f));  // 1 - 2/(e+1)
}

__global__ __launch_bounds__(256) void pinn_fields_kernel(
    const float* __restrict__ x,
    const float* __restrict__ W1,   // (16,1)
    const float* __restrict__ b1,   // (16,)
    const float* __restrict__ W2,   // (16,16) row-major
    const float* __restrict__ b2,   // (16,)
    const float* __restrict__ W3,   // (2,16) row-major
    const float* __restrict__ b3,   // (2,)
    float* __restrict__ out,        // 6 * n, concatenated (u,w,wx,N,M,Q)
    int n)
{
    int idx = blockIdx.x * blockDim.x + threadIdx.x;
    if (idx >= n) return;

    float z = x[idx];  // z = x / L, L = 1
    v2f zz = splat2(z);
    v2f one = splat2(1.0f);

    // ---- layer 1, j-packed: H0={h}, H1={h_x}, H2={h_xx}, H3={h_xxx} ----
    v2f H0[8], H1[8], H2[8], H3[8];
#pragma unroll
    for (int jp = 0; jp < 8; ++jp) {
        v2f c  = *(const v2f*)(W1 + 2 * jp);   // 8B-aligned, wave-uniform
        v2f bb = *(const v2f*)(b1 + 2 * jp);
        v2f a  = pk_fma(c, zz, bb);
        v2f t  = pk_tanh(a);
        v2f s  = pk_fma(-t, t, one);           // sech^2 = 1 - t^2
        v2f c2 = c * c;
        v2f c3 = c2 * c;
        v2f m  = t * s;
        v2f p  = pk_fma(splat2(-6.0f), s, splat2(4.0f));   // 4 - 6s = 6t^2 - 2
        H0[jp] = t;
        H1[jp] = s * c;                        // t' * c
        H2[jp] = m * (c2 * splat2(-2.0f));     // -2 t s * c^2
        H3[jp] = (s * p) * c3;                 // s(6t^2-2) * c^3
    }

    // ---- layer 2 (row pairs) + Faa di Bruno + layer 3 ----
    v2f Uacc0 = splat2(0.0f), Uacc1 = splat2(0.0f);
    v2f Wacc0 = splat2(0.0f), Wacc1 = splat2(0.0f);
    v2f Wacc2 = splat2(0.0f), Wacc3 = splat2(0.0f);
#pragma unroll
    for (int ip = 0; ip < 8; ++ip) {
        int i0 = 2 * ip, i1 = 2 * ip + 1;
        v2f A0a = mk2(b2[i0], 0.0f), A1a = splat2(0.0f), A2a = splat2(0.0f), A3a = splat2(0.0f);
        v2f A0b = mk2(b2[i1], 0.0f), A1b = splat2(0.0f), A2b = splat2(0.0f), A3b = splat2(0.0f);
#pragma unroll
        for (int jp = 0; jp < 8; ++jp) {
            v2f wa = *(const v2f*)(W2 + i0 * 16 + 2 * jp);  // uniform pair
            v2f wb = *(const v2f*)(W2 + i1 * 16 + 2 * jp);
            A0a = pk_fma(wa, H0[jp], A0a);
            A1a = pk_fma(wa, H1[jp], A1a);
            A2a = pk_fma(wa, H2[jp], A2a);
            A3a = pk_fma(wa, H3[jp], A3a);
            A0b = pk_fma(wb, H0[jp], A0b);
            A1b = pk_fma(wb, H1[jp], A1b);
            A2b = pk_fma(wb, H2[jp], A2b);
            A3b = pk_fma(wb, H3[jp], A3b);
        }
        // horizontal sums -> packed across the row pair
        v2f a0 = mk2(A0a.x + A0a.y, A0b.x + A0b.y);
        v2f a1 = mk2(A1a.x + A1a.y, A1b.x + A1b.y);
        v2f a2 = mk2(A2a.x + A2a.y, A2b.x + A2b.y);
        v2f a3 = mk2(A3a.x + A3a.y, A3b.x + A3b.y);

        v2f t  = pk_tanh(a0);
        v2f s  = pk_fma(-t, t, one);                         // d1
        v2f m  = t * s;
        v2f d2 = m * splat2(-2.0f);
        v2f d3 = s * pk_fma(splat2(-6.0f), s, splat2(4.0f)); // s(6t^2-2)
        v2f a1sq = a1 * a1;
        v2f g1 = s * a1;
        v2f g2 = pk_fma(d2, a1sq, s * a2);
        v2f u1 = d3 * (a1sq * a1);
        v2f v3 = (a1 * splat2(3.0f)) * a2;
        v2f g3 = pk_fma(s, a3, pk_fma(d2, v3, u1));

        v2f w3u = *(const v2f*)(W3 + i0);        // {W3[0][i0], W3[0][i1]}
        v2f w3w = *(const v2f*)(W3 + 16 + i0);   // {W3[1][i0], W3[1][i1]}
        Uacc0 = pk_fma(w3u, t,  Uacc0);
        Uacc1 = pk_fma(w3u, g1, Uacc1);
        Wacc0 = pk_fma(w3w, t,  Wacc0);
        Wacc1 = pk_fma(w3w, g1, Wacc1);
        Wacc2 = pk_fma(w3w, g2, Wacc2);
        Wacc3 = pk_fma(w3w, g3, Wacc3);
    }

    float u    = Uacc0.x + Uacc0.y + b3[0];
    float ux   = Uacc1.x + Uacc1.y;
    float w    = Wacc0.x + Wacc0.y + b3[1];
    float wx   = Wacc1.x + Wacc1.y;
    float wxx  = Wacc2.x + Wacc2.y;
    float wxxx = Wacc3.x + Wacc3.y;

    float Nax = EA_C * fmaf(0.5f * wx, wx, ux);
    float Mb  = -EI_C * wxx;
    float Qs  = fmaf(Nax, wx, -EI_C * wxxx);

    out[idx]         = u;
    out[n + idx]     = w;
    out[2 * n + idx] = wx;
    out[3 * n + idx] = Nax;
    out[4 * n + idx] = Mb;
    out[5 * n + idx] = Qs;
}

extern "C" void kernel_launch(void* const* d_in, const int* in_sizes, int n_in,
                              void* d_out, int out_size, void* d_ws, size_t ws_size,
                              hipStream_t stream) {
    const float* x  = (const float*)d_in[0];
    const float* W1 = (const float*)d_in[1];
    const float* b1 = (const float*)d_in[2];
    const float* W2 = (const float*)d_in[3];
    const float* b2 = (const float*)d_in[4];
    const float* W3 = (const float*)d_in[5];
    const float* b3 = (const float*)d_in[6];
    float* out = (float*)d_out;
    int n = in_sizes[0];

    int block = 256;
    int grid = (n + block - 1) / block;
    pinn_fields_kernel<<<grid, block, 0, stream>>>(x, W1, b1, W2, b2, W3, b3, out, n);
}